// Round 19
// baseline (3176.509 us; speedup 1.0000x reference)
//
#include <hip/hip_runtime.h>
#include <hip/hip_bf16.h>

// Leaky tanh RNN, persistent cooperative kernel (round 19: R13 + two latency
// reorderings). 8 chains (batch-groups of 8), 128 WGs; WG (pid,role) owns
// col-slice [32r,32r+32) of wrec/wi/wo for chains A=2pid, B=2pid+1 (LDS).
// Per half: compute chain C step i, prep chain D step j.
// CHANGES vs R13 (both pure reorderings, protocol semantics identical):
//  1. pv (D's flag poll) issued MID-MFMA (after kt=3) — its MALL RT overlaps
//     the back half of the MFMA block instead of being fully exposed at 2.6.
//  2. Producer tail order: g-stores -> seed-MFMAs -> vmcnt(0) -> publish.
//     Store acks fly under seed compute; publish still strictly after drain.
//     Confirm now precedes publish in program order — safe: confirm waits only
//     on PREVIOUS-half publishes (monotone, no cycle).
// All waits vmcnt(0) (counted vmcnt banned, R12/R14). All g/flag ops sc0 sc1.

#define T_ 512
#define I_ 128
#define H_ 1024
#define O_ 64
#define NWG 128
#define POLL_CAP (1<<17)

// workspace
#define GBUF_BYTES (8*2*8*H_*2)          // 262144
#define STEPFLAG_OFF GBUF_BYTES          // u16[8][64] = 1024 B
#define WS_NEED (GBUF_BYTES + 1024)      // 263168 (proven footprint)

// LDS (bf16 element offsets for weights; byte offsets for f32 regions)
#define WREC_HI_E 0
#define WREC_LO_E 32768
#define WI_HI_E   65536
#define WI_LO_E   69632
#define WO_HI_E   73728
#define WO_LO_E   75776
#define RED_OFF_B   155648   // 9 slots * 32 lanes * 16B
#define NSA_OFF_B   160256   // 8*32 f32
#define NSB_OFF_B   161280
#define LDS_BYTES   162304

typedef __bf16 bf16x8 __attribute__((ext_vector_type(8)));
typedef float f32x4 __attribute__((ext_vector_type(4)));
typedef unsigned u32x4 __attribute__((ext_vector_type(4)));
typedef unsigned short u16;

__device__ __forceinline__ float fast_tanh(float v){
  float cx = fminf(fmaxf(v, -14.f), 14.f);
  float e = __builtin_amdgcn_exp2f(cx * 2.8853900817779268f);
  return 1.f - 2.f * __builtin_amdgcn_rcpf(e + 1.f);
}

// ---- system-scope comm primitives (proven R5-R13) ----
__device__ __forceinline__ void flag_issue(unsigned& v, const u16* p){
  asm volatile("global_load_ushort %0, %1, off sc0 sc1" : "=v"(v) : "v"(p));
}
__device__ __forceinline__ unsigned sflag_load(const u16* p){
  unsigned v;
  asm volatile("global_load_ushort %0, %1, off sc0 sc1\n\ts_waitcnt vmcnt(0)"
               : "=v"(v) : "v"(p) : "memory");
  return v;
}
__device__ __forceinline__ void sflag_store(u16* p, unsigned v){
  asm volatile("global_store_short %0, %1, off sc0 sc1" :: "v"(p), "v"(v) : "memory");
}
__device__ __forceinline__ void g_load_frag(u32x4& d, const u16* p){
  asm volatile("global_load_dwordx4 %0, %1, off sc0 sc1" : "=v"(d) : "v"(p) : "memory");
}
__device__ __forceinline__ void g_store_u16(u16* p, unsigned v){
  asm volatile("global_store_short %0, %1, off sc0 sc1" :: "v"(p), "v"(v) : "memory");
}
__device__ __forceinline__ void g_store_f32(float* p, float v){
  asm volatile("global_store_dword %0, %1, off" :: "v"(p), "v"(v) : "memory");
}
// plain cached input loads (x / noise); vmcnt bookkeeping manual
__device__ __forceinline__ void gl_f32x4(f32x4& d, const float* p){
  asm volatile("global_load_dwordx4 %0, %1, off" : "=v"(d) : "v"(p));
}
__device__ __forceinline__ void gl_f32(float& d, const float* p){
  asm volatile("global_load_dword %0, %1, off" : "=v"(d) : "v"(p));
}
// execution barrier + LDS ordering only: does NOT drain vmcnt
__device__ __forceinline__ void barrier_lds(){
  asm volatile("s_waitcnt lgkmcnt(0)\n\ts_barrier" ::: "memory");
}

// [K x 32] col-slice of row-major [K x ld] fp32 -> LDS split bf16 (hi+lo),
// pre-swizzled into MFMA B-frag order (verified rounds 1-13).
__device__ void load_slice(const float* __restrict__ Wg, int ld, int c0, int K,
                           __bf16* hi, __bf16* lo){
  for (int idx = threadIdx.x; idx < K*32; idx += 256){
    int k = idx >> 5, c = idx & 31;
    float v = Wg[(size_t)k*ld + c0 + c];
    __bf16 h = (__bf16)v;
    __bf16 l = (__bf16)(v - (float)h);
    int kt = k >> 5, kin = k & 31, lg = kin >> 3, j = kin & 7;
    int off = (((kt*2 + (c>>4))*64 + (lg*16 + (c&15))) << 3) + j;
    hi[off] = h; lo[off] = l;
  }
}

#define MFMA __builtin_amdgcn_mfma_f32_16x16x32_bf16
#define BC(u) __builtin_bit_cast(bf16x8, u)

struct Chain {
  u32x4 a[8];          // prefetched g A-frags
  f32x4 h0, xA, xB;    // h state, x@wi seeds (hi/lo passes)
  u16 *gg, *gf;
  const u16 *ab;       // per-lane A-frag base into gg
  const float *xb, *nb;
  float *ob;
  float *NS;           // LDS noise stage for this chain
};

// one MFMA k-step for chain C
#define MSTEP(KT)                                                             \
  { const int kg = kb + KT;                                                   \
    bf16x8 bh0 = *(const bf16x8*)(B + WREC_HI_E + kg*1024 + bf);              \
    bf16x8 bl0 = *(const bf16x8*)(B + WREC_LO_E + kg*1024 + bf);              \
    bf16x8 bh1 = *(const bf16x8*)(B + WREC_HI_E + kg*1024 + 512 + bf);        \
    bf16x8 bl1 = *(const bf16x8*)(B + WREC_LO_E + kg*1024 + 512 + bf);        \
    bf16x8 wh  = *(const bf16x8*)(B + WO_HI_E + wo_off + kg*32);              \
    bf16x8 wl  = *(const bf16x8*)(B + WO_LO_E + wo_off + kg*32);              \
    bf16x8 av = BC(C.a[KT]);                                                  \
    c0A = MFMA(av, bh0, c0A, 0,0,0);  c0B = MFMA(av, bl0, c0B, 0,0,0);        \
    c1A = MFMA(av, bh1, c1A, 0,0,0);  c1B = MFMA(av, bl1, c1B, 0,0,0);        \
    oA  = MFMA(av, wh,  oA,  0,0,0);  oB  = MFMA(av, wl,  oB,  0,0,0); }

// compute chain C step i; prepare chain D step j (j==T_ -> g loads only)
__device__ __forceinline__ void do_half(
    Chain& C, Chain& D, int i, int j,
    __bf16* B, float* RED,
    int lane, int w, int lhalf, int l15, int bf, int wo_off, int c0, int role)
{
  // 1: complete C's g_i A-frag loads
  asm volatile("s_waitcnt vmcnt(0)"
    : "+v"(C.a[0]),"+v"(C.a[1]),"+v"(C.a[2]),"+v"(C.a[3]),
      "+v"(C.a[4]),"+v"(C.a[5]),"+v"(C.a[6]),"+v"(C.a[7]) :: "memory");
  __builtin_amdgcn_sched_barrier(0);

  // 1.5: early-issue D's inputs (latency hides under C's MFMAs)
  f32x4 xv0,xv1,xv2,xv3,xv4,xv5,xv6,xv7;
  float n0,n1,n2,n3;
  if (j < T_){
    if (w < 2){
      const float* xp = D.xb + ((size_t)(l15 & 7)*T_ + (size_t)j)*I_ + lhalf*8;
      gl_f32x4(xv0, xp);      gl_f32x4(xv1, xp+4);
      gl_f32x4(xv2, xp+32);   gl_f32x4(xv3, xp+36);
      gl_f32x4(xv4, xp+64);   gl_f32x4(xv5, xp+68);
      gl_f32x4(xv6, xp+96);   gl_f32x4(xv7, xp+100);
    } else if (w == 3){
      const int b0 = lane >> 5, cc = lane & 31;
      gl_f32(n0, D.nb + ((size_t)(b0+0)*T_ + j)*H_ + c0 + cc);
      gl_f32(n1, D.nb + ((size_t)(b0+2)*T_ + j)*H_ + c0 + cc);
      gl_f32(n2, D.nb + ((size_t)(b0+4)*T_ + j)*H_ + c0 + cc);
      gl_f32(n3, D.nb + ((size_t)(b0+6)*T_ + j)*H_ + c0 + cc);
    }
  }

  // 2: MFMAs for C; pv issued MID-BLOCK so its RT overlaps kt=4..7
  f32x4 c0A={0.f,0.f,0.f,0.f}, c0B={0.f,0.f,0.f,0.f};
  f32x4 c1A={0.f,0.f,0.f,0.f}, c1B={0.f,0.f,0.f,0.f};
  f32x4 oA ={0.f,0.f,0.f,0.f}, oB ={0.f,0.f,0.f,0.f};
  if (w == 0){ c0A = C.xA; c0B = C.xB; }
  if (w == 1){ c1A = C.xA; c1B = C.xB; }
  const int kb = w*8;
  MSTEP(0) MSTEP(1) MSTEP(2) MSTEP(3)
  __builtin_amdgcn_sched_barrier(0);
  unsigned pv; flag_issue(pv, D.gf + lane);
  __builtin_amdgcn_sched_barrier(0);
  MSTEP(4) MSTEP(5) MSTEP(6) MSTEP(7)
  f32x4 cn0 = c0A + c0B, cn1 = c1A + c1B, co = oA + oB;

  // 2.6: retire pv (+inputs) — loads only, full drain (pv RT mostly flown)
  if (j < T_ && w < 2){
    asm volatile("s_waitcnt vmcnt(0)"
      : "+v"(pv),"+v"(xv0),"+v"(xv1),"+v"(xv2),"+v"(xv3),
        "+v"(xv4),"+v"(xv5),"+v"(xv6),"+v"(xv7) :: "memory");
  } else if (j < T_ && w == 3){
    asm volatile("s_waitcnt vmcnt(0)"
      : "+v"(pv),"+v"(n0),"+v"(n1),"+v"(n2),"+v"(n3) :: "memory");
  } else {
    asm volatile("s_waitcnt vmcnt(0)" : "+v"(pv) :: "memory");
  }
  __builtin_amdgcn_sched_barrier(0);

  // 2.7: confirm D's flags (fast path expected; slow path = proven R6 loop)
  {
    const unsigned tgt = (unsigned)j;
    if (!__all((int)(pv >= tgt))){
      int guard = 0;
      while (true){
        unsigned v = sflag_load(D.gf + lane);
        if (__all((int)(v >= tgt))) break;
        if (++guard > POLL_CAP) break;   // bail: wrong answer beats a hang
      }
    }
  }
  // 2.8: issue D's a-loads — long flight; drained by producer's final vmcnt(0)
  {
    const u16* ap = D.ab + (size_t)(j & 1)*(8*H_);
    #pragma unroll
    for (int kt = 0; kt < 8; ++kt) g_load_frag(D.a[kt], ap + kt*32);
  }

  // 3: cross-wave partials
  if (lane < 32){
    if (w == 0){ *(f32x4*)&RED[((1*3+0)*32+lane)*4] = cn1; *(f32x4*)&RED[((2*3+0)*32+lane)*4] = co; }
    if (w == 1){ *(f32x4*)&RED[((0*3+0)*32+lane)*4] = cn0; *(f32x4*)&RED[((2*3+1)*32+lane)*4] = co; }
    if (w == 2){ *(f32x4*)&RED[((0*3+1)*32+lane)*4] = cn0; *(f32x4*)&RED[((1*3+1)*32+lane)*4] = cn1; }
    if (w == 3){ *(f32x4*)&RED[((0*3+2)*32+lane)*4] = cn0; *(f32x4*)&RED[((1*3+2)*32+lane)*4] = cn1; *(f32x4*)&RED[((2*3+2)*32+lane)*4] = co; }
  }
  barrier_lds();

  // 4: owners reduce + h update + g_{i+1} stores; w2 computes out[i-1]
  f32x4 so_out = {0.f,0.f,0.f,0.f};
  bool do_out = false;
  if (w < 2 && lane < 32){
    const int fbase = w ? 3 : 0;
    f32x4 s = w ? cn1 : cn0;
    s += *(f32x4*)&RED[((fbase+0)*32+lane)*4];
    s += *(f32x4*)&RED[((fbase+1)*32+lane)*4];
    s += *(f32x4*)&RED[((fbase+2)*32+lane)*4];
    u16* gp = C.gg + (size_t)((i+1)&1)*(8*H_);
    #pragma unroll
    for (int r = 0; r < 4; ++r){
      int row = lhalf*4 + r;
      float hv = 0.9f*C.h0[r] + 0.1f*s[r] + 0.002f*C.NS[row*32 + w*16 + l15];
      C.h0[r] = hv;
      u16 gv = __builtin_bit_cast(u16, (__bf16)fast_tanh(hv));
      g_store_u16(gp + (size_t)row*H_ + c0 + w*16 + l15, (unsigned)gv);
    }
  }
  if (w == 2 && lane < 32 && i > 0){
    f32x4 s = co;
    s += *(f32x4*)&RED[((2*3+0)*32+lane)*4];
    s += *(f32x4*)&RED[((2*3+1)*32+lane)*4];
    s += *(f32x4*)&RED[((2*3+2)*32+lane)*4];
    so_out = s;
    do_out = (l15 < 2);
  }

  // 4.4 / 4.5 / 4.6 (producers): seeds UNDER store flight -> drain -> publish
  if (w < 2){
    if (j < T_){
      f32x4 nxA = {0.f,0.f,0.f,0.f}, nxB = {0.f,0.f,0.f,0.f};
      #pragma unroll
      for (int kt = 0; kt < 4; ++kt){
        f32x4 v0 = (kt==0)?xv0:(kt==1)?xv2:(kt==2)?xv4:xv6;
        f32x4 v1 = (kt==0)?xv1:(kt==1)?xv3:(kt==2)?xv5:xv7;
        bf16x8 xh, xl;
        #pragma unroll
        for (int jj = 0; jj < 4; ++jj){
          float aa = v0[jj], bb = v1[jj];
          __bf16 ah = (__bf16)aa, bh2 = (__bf16)bb;
          xh[jj] = ah; xh[jj+4] = bh2;
          xl[jj] = (__bf16)(aa - (float)ah); xl[jj+4] = (__bf16)(bb - (float)bh2);
        }
        bf16x8 wih = *(const bf16x8*)(B + WI_HI_E + kt*1024 + w*512 + bf);
        bf16x8 wil = *(const bf16x8*)(B + WI_LO_E + kt*1024 + w*512 + bf);
        nxA = MFMA(xh, wih, nxA, 0,0,0);
        nxB = MFMA(xl, wih, nxB, 0,0,0);
        nxA = MFMA(xh, wil, nxA, 0,0,0);
      }
      D.xA = nxA; D.xB = nxB;
    }
    asm volatile("s_waitcnt vmcnt(0)" ::: "memory");   // g-stores + a-loads done
    if (lane == 0) sflag_store(C.gf + role*2 + w, (unsigned)(i+1));
  } else if (w == 2){
    if (do_out){   // deferred outs: acks ride to next half's sec-1 drain
      #pragma unroll
      for (int r = 0; r < 4; ++r){
        int row = lhalf*4 + r;
        g_store_f32(&C.ob[((size_t)row*T_ + (i-1))*O_ + role*2 + l15], so_out[r]);
      }
    }
  } else { // w == 3
    if (j < T_){
      const int b0 = lane >> 5, cc = lane & 31;
      D.NS[(b0+0)*32 + cc] = n0;
      D.NS[(b0+2)*32 + cc] = n1;
      D.NS[(b0+4)*32 + cc] = n2;
      D.NS[(b0+6)*32 + cc] = n3;
    }
  }

  // 6: end-of-half barrier (RED reuse + NS visibility)
  barrier_lds();
}

// prologue prep of chain D step 0 (flags trivially satisfied; g_0 is zeroed)
__device__ __forceinline__ void prep0(Chain& D, __bf16* B,
    int lane, int w, int lhalf, int l15, int bf, int c0)
{
  f32x4 xv0,xv1,xv2,xv3,xv4,xv5,xv6,xv7;
  float n0,n1,n2,n3;
  if (w < 2){
    const float* xp = D.xb + (size_t)(l15 & 7)*T_*I_ + lhalf*8;
    gl_f32x4(xv0, xp);      gl_f32x4(xv1, xp+4);
    gl_f32x4(xv2, xp+32);   gl_f32x4(xv3, xp+36);
    gl_f32x4(xv4, xp+64);   gl_f32x4(xv5, xp+68);
    gl_f32x4(xv6, xp+96);   gl_f32x4(xv7, xp+100);
    asm volatile("s_waitcnt vmcnt(0)"
      : "+v"(xv0),"+v"(xv1),"+v"(xv2),"+v"(xv3),
        "+v"(xv4),"+v"(xv5),"+v"(xv6),"+v"(xv7) :: "memory");
  } else if (w == 3){
    const int b0 = lane >> 5, cc = lane & 31;
    gl_f32(n0, D.nb + (size_t)(b0+0)*T_*H_ + c0 + cc);
    gl_f32(n1, D.nb + (size_t)(b0+2)*T_*H_ + c0 + cc);
    gl_f32(n2, D.nb + (size_t)(b0+4)*T_*H_ + c0 + cc);
    gl_f32(n3, D.nb + (size_t)(b0+6)*T_*H_ + c0 + cc);
    asm volatile("s_waitcnt vmcnt(0)"
      : "+v"(n0),"+v"(n1),"+v"(n2),"+v"(n3) :: "memory");
  }
  __builtin_amdgcn_sched_barrier(0);
  #pragma unroll
  for (int kt = 0; kt < 8; ++kt) g_load_frag(D.a[kt], D.ab + kt*32);
  if (w < 2){
    f32x4 nxA = {0.f,0.f,0.f,0.f}, nxB = {0.f,0.f,0.f,0.f};
    #pragma unroll
    for (int kt = 0; kt < 4; ++kt){
      f32x4 v0 = (kt==0)?xv0:(kt==1)?xv2:(kt==2)?xv4:xv6;
      f32x4 v1 = (kt==0)?xv1:(kt==1)?xv3:(kt==2)?xv5:xv7;
      bf16x8 xh, xl;
      #pragma unroll
      for (int jj = 0; jj < 4; ++jj){
        float aa = v0[jj], bb = v1[jj];
        __bf16 ah = (__bf16)aa, bh2 = (__bf16)bb;
        xh[jj] = ah; xh[jj+4] = bh2;
        xl[jj] = (__bf16)(aa - (float)ah); xl[jj+4] = (__bf16)(bb - (float)bh2);
      }
      bf16x8 wih = *(const bf16x8*)(B + WI_HI_E + kt*1024 + w*512 + bf);
      bf16x8 wil = *(const bf16x8*)(B + WI_LO_E + kt*1024 + w*512 + bf);
      nxA = MFMA(xh, wih, nxA, 0,0,0);
      nxB = MFMA(xl, wih, nxB, 0,0,0);
      nxA = MFMA(xh, wil, nxA, 0,0,0);
    }
    D.xA = nxA; D.xB = nxB;
  } else if (w == 3){
    const int b0 = lane >> 5, cc = lane & 31;
    D.NS[(b0+0)*32 + cc] = n0;
    D.NS[(b0+2)*32 + cc] = n1;
    D.NS[(b0+4)*32 + cc] = n2;
    D.NS[(b0+6)*32 + cc] = n3;
  }
  barrier_lds();
}

// epilogue: out[T-1] = g_T @ wo for chain C (C.a holds g_T frags)
__device__ __forceinline__ void epi(Chain& C, __bf16* B, float* RED,
    int lane, int w, int lhalf, int l15, int bf, int wo_off, int role)
{
  asm volatile("s_waitcnt vmcnt(0)"
    : "+v"(C.a[0]),"+v"(C.a[1]),"+v"(C.a[2]),"+v"(C.a[3]),
      "+v"(C.a[4]),"+v"(C.a[5]),"+v"(C.a[6]),"+v"(C.a[7]) :: "memory");
  __builtin_amdgcn_sched_barrier(0);
  f32x4 oA={0.f,0.f,0.f,0.f}, oB={0.f,0.f,0.f,0.f};
  const int kb = w*8;
  #pragma unroll
  for (int kt = 0; kt < 8; ++kt){
    const int kg = kb + kt;
    bf16x8 wh = *(const bf16x8*)(B + WO_HI_E + wo_off + kg*32);
    bf16x8 wl = *(const bf16x8*)(B + WO_LO_E + wo_off + kg*32);
    bf16x8 av = BC(C.a[kt]);
    oA = MFMA(av, wh, oA, 0,0,0);  oB = MFMA(av, wl, oB, 0,0,0);
  }
  f32x4 co = oA + oB;
  barrier_lds();   // prior RED consumers done
  if (lane < 32){
    if (w == 0) *(f32x4*)&RED[((2*3+0)*32+lane)*4] = co;
    if (w == 1) *(f32x4*)&RED[((2*3+1)*32+lane)*4] = co;
    if (w == 3) *(f32x4*)&RED[((2*3+2)*32+lane)*4] = co;
  }
  barrier_lds();
  if (w == 2 && lane < 32){
    f32x4 s = co;
    s += *(f32x4*)&RED[((2*3+0)*32+lane)*4];
    s += *(f32x4*)&RED[((2*3+1)*32+lane)*4];
    s += *(f32x4*)&RED[((2*3+2)*32+lane)*4];
    if (l15 < 2){
      #pragma unroll
      for (int r = 0; r < 4; ++r){
        int row = lhalf*4 + r;
        C.ob[((size_t)row*T_ + (T_-1))*O_ + role*2 + l15] = s[r];
      }
    }
  }
}

extern "C" __global__ __launch_bounds__(256, 1)
void rnn_kernel(const float* __restrict__ x, const float* __restrict__ noise,
                const float* __restrict__ wi, const float* __restrict__ wrec,
                const float* __restrict__ wo, float* __restrict__ out,
                u16* __restrict__ gbuf, u16* __restrict__ sflags)
{
  extern __shared__ char smem[];
  __bf16* B = (__bf16*)smem;
  float* RED = (float*)(smem + RED_OFF_B);

  const int pid  = blockIdx.x >> 5;
  const int role = blockIdx.x & 31;
  const int c0 = role * 32;

  load_slice(wrec, H_, c0, H_, B + WREC_HI_E, B + WREC_LO_E);
  load_slice(wi,   H_, c0, I_, B + WI_HI_E,  B + WI_LO_E);
  for (int idx = threadIdx.x; idx < 2*H_; idx += 256){
    int col = idx >> 10, k = idx & (H_-1);
    float v = wo[(size_t)k*O_ + role*2 + col];
    __bf16 hh = (__bf16)v;
    B[WO_HI_E + col*H_ + k] = hh;
    B[WO_LO_E + col*H_ + k] = (__bf16)(v - (float)hh);
  }
  __syncthreads();

  const int lane = threadIdx.x & 63;
  const int w    = threadIdx.x >> 6;
  const int lhalf = lane >> 4;
  const int l15   = lane & 15;
  const int bf = lane * 8;
  const int wo_off = (l15 & 1)*1024 + lhalf*8;

  Chain A, Bc;
  const int gA = pid*2, gB = pid*2+1;
  A.gg  = gbuf + gA*(2*8*H_);   A.gf  = sflags + gA*64;
  Bc.gg = gbuf + gB*(2*8*H_);   Bc.gf = sflags + gB*64;
  A.ab  = A.gg  + (size_t)(lane & 7)*H_ + w*256 + lhalf*8;
  Bc.ab = Bc.gg + (size_t)(lane & 7)*H_ + w*256 + lhalf*8;
  A.xb  = x + (size_t)(gA*8)*T_*I_;     Bc.xb = x + (size_t)(gB*8)*T_*I_;
  A.nb  = noise + (size_t)(gA*8)*T_*H_; Bc.nb = noise + (size_t)(gB*8)*T_*H_;
  A.ob  = out + (size_t)(gA*8)*T_*O_;   Bc.ob = out + (size_t)(gB*8)*T_*O_;
  A.NS  = (float*)(smem + NSA_OFF_B);   Bc.NS = (float*)(smem + NSB_OFF_B);
  A.h0  = (f32x4){0.f,0.f,0.f,0.f};     Bc.h0 = (f32x4){0.f,0.f,0.f,0.f};
  A.xA  = (f32x4){0.f,0.f,0.f,0.f};     A.xB  = (f32x4){0.f,0.f,0.f,0.f};
  Bc.xA = (f32x4){0.f,0.f,0.f,0.f};     Bc.xB = (f32x4){0.f,0.f,0.f,0.f};

  prep0(A, B, lane, w, lhalf, l15, bf, c0);

  for (int i = 0; i < T_; ++i){
    do_half(A,  Bc, i, i,   B, RED, lane, w, lhalf, l15, bf, wo_off, c0, role);
    do_half(Bc, A,  i, i+1, B, RED, lane, w, lhalf, l15, bf, wo_off, c0, role);
  }

  epi(A, B, RED, lane, w, lhalf, l15, bf, wo_off, role);
  { // fetch B's g_T (not prefetched) and finish
    int guard = 0;
    while (true){
      unsigned v = sflag_load(Bc.gf + lane);
      if (__all((int)(v >= (unsigned)T_))) break;
      if (++guard > POLL_CAP) break;
    }
    #pragma unroll
    for (int kt = 0; kt < 8; ++kt) g_load_frag(Bc.a[kt], Bc.ab + kt*32); // parity T&1==0
  }
  epi(Bc, B, RED, lane, w, lhalf, l15, bf, wo_off, role);
}

extern "C" void kernel_launch(void* const* d_in, const int* in_sizes, int n_in,
                              void* d_out, int out_size, void* d_ws, size_t ws_size,
                              hipStream_t stream){
  const float* x     = (const float*)d_in[0];
  const float* noise = (const float*)d_in[1];
  const float* wi    = (const float*)d_in[2];
  const float* wrec  = (const float*)d_in[3];
  const float* wo    = (const float*)d_in[4];
  float* out = (float*)d_out;

  if (ws_size < (size_t)WS_NEED) return;
  u16* gbuf = (u16*)d_ws;
  u16* sflags = (u16*)((char*)d_ws + STEPFLAG_OFF);

  hipMemsetAsync(d_ws, 0, WS_NEED, stream);   // zero g_0 + flags

  hipFuncSetAttribute((const void*)rnn_kernel,
                      hipFuncAttributeMaxDynamicSharedMemorySize, LDS_BYTES);

  void* args[] = {(void*)&x, (void*)&noise, (void*)&wi, (void*)&wrec, (void*)&wo,
                  (void*)&out, (void*)&gbuf, (void*)&sflags};
  hipLaunchCooperativeKernel((const void*)rnn_kernel, dim3(NWG), dim3(256),
                             args, LDS_BYTES, stream);
}

// Round 20
// 2873.580 us; speedup vs baseline: 1.1054x; 1.1054x over previous
//
#include <hip/hip_runtime.h>
#include <hip/hip_bf16.h>

// Leaky tanh RNN, persistent cooperative kernel (round 20: R13 verbatim —
// restoring the measured optimum, 2872us). 8 chains (batch-groups of 8),
// 128 WGs; WG (pid,role) owns col-slice [32r,32r+32) of wrec/wi/wo for chains
// A=2pid, B=2pid+1 (LDS). Per half: compute chain C step i, prep chain D
// step j. All waits vmcnt(0) (counted vmcnt banned: any in-flight store
// breaks counted-wait semantics — R12/R14). Protocol: sc0 sc1 on all g/flag
// ops (MALL coherence point); g-stores drained before flag publish; late pv
// sample (after MFMA block) -> fast-path confirm; confirm strictly before
// a-load issue; w2 out-stores deferred past confirm.
// Cycle anatomy (measured): step = 5.6us = work 1.5 + ~4 MALL RTs. Eight
// restructurings (R14-R19) all failed to shrink it; this is the floor.

#define T_ 512
#define I_ 128
#define H_ 1024
#define O_ 64
#define NWG 128
#define POLL_CAP (1<<17)

// workspace
#define GBUF_BYTES (8*2*8*H_*2)          // 262144
#define STEPFLAG_OFF GBUF_BYTES          // u16[8][64] = 1024 B
#define WS_NEED (GBUF_BYTES + 1024)      // 263168 (proven footprint)

// LDS (bf16 element offsets for weights; byte offsets for f32 regions)
#define WREC_HI_E 0
#define WREC_LO_E 32768
#define WI_HI_E   65536
#define WI_LO_E   69632
#define WO_HI_E   73728
#define WO_LO_E   75776
#define RED_OFF_B   155648   // 9 slots * 32 lanes * 16B
#define NSA_OFF_B   160256   // 8*32 f32
#define NSB_OFF_B   161280
#define LDS_BYTES   162304

typedef __bf16 bf16x8 __attribute__((ext_vector_type(8)));
typedef float f32x4 __attribute__((ext_vector_type(4)));
typedef unsigned u32x4 __attribute__((ext_vector_type(4)));
typedef unsigned short u16;

__device__ __forceinline__ float fast_tanh(float v){
  float cx = fminf(fmaxf(v, -14.f), 14.f);
  float e = __builtin_amdgcn_exp2f(cx * 2.8853900817779268f);
  return 1.f - 2.f * __builtin_amdgcn_rcpf(e + 1.f);
}

// ---- system-scope comm primitives (proven R5-R13) ----
__device__ __forceinline__ void flag_issue(unsigned& v, const u16* p){
  asm volatile("global_load_ushort %0, %1, off sc0 sc1" : "=v"(v) : "v"(p));
}
__device__ __forceinline__ unsigned sflag_load(const u16* p){
  unsigned v;
  asm volatile("global_load_ushort %0, %1, off sc0 sc1\n\ts_waitcnt vmcnt(0)"
               : "=v"(v) : "v"(p) : "memory");
  return v;
}
__device__ __forceinline__ void sflag_store(u16* p, unsigned v){
  asm volatile("global_store_short %0, %1, off sc0 sc1" :: "v"(p), "v"(v) : "memory");
}
__device__ __forceinline__ void g_load_frag(u32x4& d, const u16* p){
  asm volatile("global_load_dwordx4 %0, %1, off sc0 sc1" : "=v"(d) : "v"(p) : "memory");
}
__device__ __forceinline__ void g_store_u16(u16* p, unsigned v){
  asm volatile("global_store_short %0, %1, off sc0 sc1" :: "v"(p), "v"(v) : "memory");
}
__device__ __forceinline__ void g_store_f32(float* p, float v){
  asm volatile("global_store_dword %0, %1, off" :: "v"(p), "v"(v) : "memory");
}
// plain cached input loads (x / noise); vmcnt bookkeeping manual
__device__ __forceinline__ void gl_f32x4(f32x4& d, const float* p){
  asm volatile("global_load_dwordx4 %0, %1, off" : "=v"(d) : "v"(p));
}
__device__ __forceinline__ void gl_f32(float& d, const float* p){
  asm volatile("global_load_dword %0, %1, off" : "=v"(d) : "v"(p));
}
// execution barrier + LDS ordering only: does NOT drain vmcnt
__device__ __forceinline__ void barrier_lds(){
  asm volatile("s_waitcnt lgkmcnt(0)\n\ts_barrier" ::: "memory");
}

// [K x 32] col-slice of row-major [K x ld] fp32 -> LDS split bf16 (hi+lo),
// pre-swizzled into MFMA B-frag order (verified rounds 1-13).
__device__ void load_slice(const float* __restrict__ Wg, int ld, int c0, int K,
                           __bf16* hi, __bf16* lo){
  for (int idx = threadIdx.x; idx < K*32; idx += 256){
    int k = idx >> 5, c = idx & 31;
    float v = Wg[(size_t)k*ld + c0 + c];
    __bf16 h = (__bf16)v;
    __bf16 l = (__bf16)(v - (float)h);
    int kt = k >> 5, kin = k & 31, lg = kin >> 3, j = kin & 7;
    int off = (((kt*2 + (c>>4))*64 + (lg*16 + (c&15))) << 3) + j;
    hi[off] = h; lo[off] = l;
  }
}

#define MFMA __builtin_amdgcn_mfma_f32_16x16x32_bf16
#define BC(u) __builtin_bit_cast(bf16x8, u)

struct Chain {
  u32x4 a[8];          // prefetched g A-frags
  f32x4 h0, xA, xB;    // h state, x@wi seeds (hi/lo passes)
  u16 *gg, *gf;
  const u16 *ab;       // per-lane A-frag base into gg
  const float *xb, *nb;
  float *ob;
  float *NS;           // LDS noise stage for this chain
};

// compute chain C step i; prepare chain D step j (j==T_ -> g loads only)
__device__ __forceinline__ void do_half(
    Chain& C, Chain& D, int i, int j,
    __bf16* B, float* RED,
    int lane, int w, int lhalf, int l15, int bf, int wo_off, int c0, int role)
{
  // 1: complete C's g_i A-frag loads (long flight since 2.8 of prev half)
  asm volatile("s_waitcnt vmcnt(0)"
    : "+v"(C.a[0]),"+v"(C.a[1]),"+v"(C.a[2]),"+v"(C.a[3]),
      "+v"(C.a[4]),"+v"(C.a[5]),"+v"(C.a[6]),"+v"(C.a[7]) :: "memory");
  __builtin_amdgcn_sched_barrier(0);

  // 1.5: early-issue D's inputs (latency hides under C's MFMAs)
  f32x4 xv0,xv1,xv2,xv3,xv4,xv5,xv6,xv7;
  float n0,n1,n2,n3;
  if (j < T_){
    if (w < 2){
      const float* xp = D.xb + ((size_t)(l15 & 7)*T_ + (size_t)j)*I_ + lhalf*8;
      gl_f32x4(xv0, xp);      gl_f32x4(xv1, xp+4);
      gl_f32x4(xv2, xp+32);   gl_f32x4(xv3, xp+36);
      gl_f32x4(xv4, xp+64);   gl_f32x4(xv5, xp+68);
      gl_f32x4(xv6, xp+96);   gl_f32x4(xv7, xp+100);
    } else if (w == 3){
      const int b0 = lane >> 5, cc = lane & 31;
      gl_f32(n0, D.nb + ((size_t)(b0+0)*T_ + j)*H_ + c0 + cc);
      gl_f32(n1, D.nb + ((size_t)(b0+2)*T_ + j)*H_ + c0 + cc);
      gl_f32(n2, D.nb + ((size_t)(b0+4)*T_ + j)*H_ + c0 + cc);
      gl_f32(n3, D.nb + ((size_t)(b0+6)*T_ + j)*H_ + c0 + cc);
    }
  }

  // 2: MFMAs for C (wrec hi/lo both halves of slice + wo hi/lo)
  f32x4 c0A={0.f,0.f,0.f,0.f}, c0B={0.f,0.f,0.f,0.f};
  f32x4 c1A={0.f,0.f,0.f,0.f}, c1B={0.f,0.f,0.f,0.f};
  f32x4 oA ={0.f,0.f,0.f,0.f}, oB ={0.f,0.f,0.f,0.f};
  if (w == 0){ c0A = C.xA; c0B = C.xB; }
  if (w == 1){ c1A = C.xA; c1B = C.xB; }
  const int kb = w*8;
  #pragma unroll
  for (int kt = 0; kt < 8; ++kt){
    const int kg = kb + kt;
    bf16x8 bh0 = *(const bf16x8*)(B + WREC_HI_E + kg*1024 + bf);
    bf16x8 bl0 = *(const bf16x8*)(B + WREC_LO_E + kg*1024 + bf);
    bf16x8 bh1 = *(const bf16x8*)(B + WREC_HI_E + kg*1024 + 512 + bf);
    bf16x8 bl1 = *(const bf16x8*)(B + WREC_LO_E + kg*1024 + 512 + bf);
    bf16x8 wh  = *(const bf16x8*)(B + WO_HI_E + wo_off + kg*32);
    bf16x8 wl  = *(const bf16x8*)(B + WO_LO_E + wo_off + kg*32);
    bf16x8 av = BC(C.a[kt]);
    c0A = MFMA(av, bh0, c0A, 0,0,0);  c0B = MFMA(av, bl0, c0B, 0,0,0);
    c1A = MFMA(av, bh1, c1A, 0,0,0);  c1B = MFMA(av, bl1, c1B, 0,0,0);
    oA  = MFMA(av, wh,  oA,  0,0,0);  oB  = MFMA(av, wl,  oB,  0,0,0);
  }
  // 2.5: poll read NOW — samples MALL well after the peers' publish
  unsigned pv; flag_issue(pv, D.gf + lane);

  f32x4 cn0 = c0A + c0B, cn1 = c1A + c1B, co = oA + oB;

  // 2.6: retire pv (+inputs) — LOADS ONLY ledger, full drain (safe)
  if (j < T_ && w < 2){
    asm volatile("s_waitcnt vmcnt(0)"
      : "+v"(pv),"+v"(xv0),"+v"(xv1),"+v"(xv2),"+v"(xv3),
        "+v"(xv4),"+v"(xv5),"+v"(xv6),"+v"(xv7) :: "memory");
  } else if (j < T_ && w == 3){
    asm volatile("s_waitcnt vmcnt(0)"
      : "+v"(pv),"+v"(n0),"+v"(n1),"+v"(n2),"+v"(n3) :: "memory");
  } else {
    asm volatile("s_waitcnt vmcnt(0)" : "+v"(pv) :: "memory");
  }
  __builtin_amdgcn_sched_barrier(0);

  // 2.7: confirm D's flags (fast path expected; slow path = proven R6 loop)
  {
    const unsigned tgt = (unsigned)j;
    if (!__all((int)(pv >= tgt))){
      int guard = 0;
      while (true){
        unsigned v = sflag_load(D.gf + lane);
        if (__all((int)(v >= tgt))) break;
        if (++guard > POLL_CAP) break;   // bail: wrong answer beats a hang
      }
    }
  }
  // 2.8: issue D's a-loads — long flight through sections 3..6
  {
    const u16* ap = D.ab + (size_t)(j & 1)*(8*H_);
    #pragma unroll
    for (int kt = 0; kt < 8; ++kt) g_load_frag(D.a[kt], ap + kt*32);
  }

  // 3: cross-wave partials
  if (lane < 32){
    if (w == 0){ *(f32x4*)&RED[((1*3+0)*32+lane)*4] = cn1; *(f32x4*)&RED[((2*3+0)*32+lane)*4] = co; }
    if (w == 1){ *(f32x4*)&RED[((0*3+0)*32+lane)*4] = cn0; *(f32x4*)&RED[((2*3+1)*32+lane)*4] = co; }
    if (w == 2){ *(f32x4*)&RED[((0*3+1)*32+lane)*4] = cn0; *(f32x4*)&RED[((1*3+1)*32+lane)*4] = cn1; }
    if (w == 3){ *(f32x4*)&RED[((0*3+2)*32+lane)*4] = cn0; *(f32x4*)&RED[((1*3+2)*32+lane)*4] = cn1; *(f32x4*)&RED[((2*3+2)*32+lane)*4] = co; }
  }
  barrier_lds();

  // 4: owners reduce + h update + g_{i+1} stores; w2 computes out[i-1]
  f32x4 so_out = {0.f,0.f,0.f,0.f};
  bool do_out = false;
  if (w < 2 && lane < 32){
    const int fbase = w ? 3 : 0;
    f32x4 s = w ? cn1 : cn0;
    s += *(f32x4*)&RED[((fbase+0)*32+lane)*4];
    s += *(f32x4*)&RED[((fbase+1)*32+lane)*4];
    s += *(f32x4*)&RED[((fbase+2)*32+lane)*4];
    u16* gp = C.gg + (size_t)((i+1)&1)*(8*H_);
    #pragma unroll
    for (int r = 0; r < 4; ++r){
      int row = lhalf*4 + r;
      float hv = 0.9f*C.h0[r] + 0.1f*s[r] + 0.002f*C.NS[row*32 + w*16 + l15];
      C.h0[r] = hv;
      u16 gv = __builtin_bit_cast(u16, (__bf16)fast_tanh(hv));
      g_store_u16(gp + (size_t)row*H_ + c0 + w*16 + l15, (unsigned)gv);
    }
  }
  if (w == 2 && lane < 32 && i > 0){
    f32x4 s = co;
    s += *(f32x4*)&RED[((2*3+0)*32+lane)*4];
    s += *(f32x4*)&RED[((2*3+1)*32+lane)*4];
    s += *(f32x4*)&RED[((2*3+2)*32+lane)*4];
    so_out = s;
    do_out = (l15 < 2);
  }

  // 5: producers drain (g-stores + own a-loads overlap in one vmcnt0), publish,
  //    then seed MFMAs for D. w2 issues deferred outs. w3 stages NS.
  if (w < 2){
    asm volatile("s_waitcnt vmcnt(0)" ::: "memory");   // stores at MALL; a-loads done
    if (lane == 0) sflag_store(C.gf + role*2 + w, (unsigned)(i+1));
    if (j < T_){
      f32x4 nxA = {0.f,0.f,0.f,0.f}, nxB = {0.f,0.f,0.f,0.f};
      #pragma unroll
      for (int kt = 0; kt < 4; ++kt){
        f32x4 v0 = (kt==0)?xv0:(kt==1)?xv2:(kt==2)?xv4:xv6;
        f32x4 v1 = (kt==0)?xv1:(kt==1)?xv3:(kt==2)?xv5:xv7;
        bf16x8 xh, xl;
        #pragma unroll
        for (int jj = 0; jj < 4; ++jj){
          float aa = v0[jj], bb = v1[jj];
          __bf16 ah = (__bf16)aa, bh2 = (__bf16)bb;
          xh[jj] = ah; xh[jj+4] = bh2;
          xl[jj] = (__bf16)(aa - (float)ah); xl[jj+4] = (__bf16)(bb - (float)bh2);
        }
        bf16x8 wih = *(const bf16x8*)(B + WI_HI_E + kt*1024 + w*512 + bf);
        bf16x8 wil = *(const bf16x8*)(B + WI_LO_E + kt*1024 + w*512 + bf);
        nxA = MFMA(xh, wih, nxA, 0,0,0);
        nxB = MFMA(xl, wih, nxB, 0,0,0);
        nxA = MFMA(xh, wil, nxA, 0,0,0);
      }
      D.xA = nxA; D.xB = nxB;
    }
  } else if (w == 2){
    if (do_out){
      #pragma unroll
      for (int r = 0; r < 4; ++r){
        int row = lhalf*4 + r;
        g_store_f32(&C.ob[((size_t)row*T_ + (i-1))*O_ + role*2 + l15], so_out[r]);
      }
    }
  } else { // w == 3
    if (j < T_){
      const int b0 = lane >> 5, cc = lane & 31;
      D.NS[(b0+0)*32 + cc] = n0;
      D.NS[(b0+2)*32 + cc] = n1;
      D.NS[(b0+4)*32 + cc] = n2;
      D.NS[(b0+6)*32 + cc] = n3;
    }
  }

  // 6: end-of-half barrier (RED reuse + NS visibility)
  barrier_lds();
}

// prologue prep of chain D step 0 (flags trivially satisfied; g_0 is zeroed)
__device__ __forceinline__ void prep0(Chain& D, __bf16* B,
    int lane, int w, int lhalf, int l15, int bf, int c0)
{
  f32x4 xv0,xv1,xv2,xv3,xv4,xv5,xv6,xv7;
  float n0,n1,n2,n3;
  if (w < 2){
    const float* xp = D.xb + (size_t)(l15 & 7)*T_*I_ + lhalf*8;
    gl_f32x4(xv0, xp);      gl_f32x4(xv1, xp+4);
    gl_f32x4(xv2, xp+32);   gl_f32x4(xv3, xp+36);
    gl_f32x4(xv4, xp+64);   gl_f32x4(xv5, xp+68);
    gl_f32x4(xv6, xp+96);   gl_f32x4(xv7, xp+100);
    asm volatile("s_waitcnt vmcnt(0)"
      : "+v"(xv0),"+v"(xv1),"+v"(xv2),"+v"(xv3),
        "+v"(xv4),"+v"(xv5),"+v"(xv6),"+v"(xv7) :: "memory");
  } else if (w == 3){
    const int b0 = lane >> 5, cc = lane & 31;
    gl_f32(n0, D.nb + (size_t)(b0+0)*T_*H_ + c0 + cc);
    gl_f32(n1, D.nb + (size_t)(b0+2)*T_*H_ + c0 + cc);
    gl_f32(n2, D.nb + (size_t)(b0+4)*T_*H_ + c0 + cc);
    gl_f32(n3, D.nb + (size_t)(b0+6)*T_*H_ + c0 + cc);
    asm volatile("s_waitcnt vmcnt(0)"
      : "+v"(n0),"+v"(n1),"+v"(n2),"+v"(n3) :: "memory");
  }
  __builtin_amdgcn_sched_barrier(0);
  #pragma unroll
  for (int kt = 0; kt < 8; ++kt) g_load_frag(D.a[kt], D.ab + kt*32);
  if (w < 2){
    f32x4 nxA = {0.f,0.f,0.f,0.f}, nxB = {0.f,0.f,0.f,0.f};
    #pragma unroll
    for (int kt = 0; kt < 4; ++kt){
      f32x4 v0 = (kt==0)?xv0:(kt==1)?xv2:(kt==2)?xv4:xv6;
      f32x4 v1 = (kt==0)?xv1:(kt==1)?xv3:(kt==2)?xv5:xv7;
      bf16x8 xh, xl;
      #pragma unroll
      for (int jj = 0; jj < 4; ++jj){
        float aa = v0[jj], bb = v1[jj];
        __bf16 ah = (__bf16)aa, bh2 = (__bf16)bb;
        xh[jj] = ah; xh[jj+4] = bh2;
        xl[jj] = (__bf16)(aa - (float)ah); xl[jj+4] = (__bf16)(bb - (float)bh2);
      }
      bf16x8 wih = *(const bf16x8*)(B + WI_HI_E + kt*1024 + w*512 + bf);
      bf16x8 wil = *(const bf16x8*)(B + WI_LO_E + kt*1024 + w*512 + bf);
      nxA = MFMA(xh, wih, nxA, 0,0,0);
      nxB = MFMA(xl, wih, nxB, 0,0,0);
      nxA = MFMA(xh, wil, nxA, 0,0,0);
    }
    D.xA = nxA; D.xB = nxB;
  } else if (w == 3){
    const int b0 = lane >> 5, cc = lane & 31;
    D.NS[(b0+0)*32 + cc] = n0;
    D.NS[(b0+2)*32 + cc] = n1;
    D.NS[(b0+4)*32 + cc] = n2;
    D.NS[(b0+6)*32 + cc] = n3;
  }
  barrier_lds();
}

// epilogue: out[T-1] = g_T @ wo for chain C (C.a holds g_T frags)
__device__ __forceinline__ void epi(Chain& C, __bf16* B, float* RED,
    int lane, int w, int lhalf, int l15, int bf, int wo_off, int role)
{
  asm volatile("s_waitcnt vmcnt(0)"
    : "+v"(C.a[0]),"+v"(C.a[1]),"+v"(C.a[2]),"+v"(C.a[3]),
      "+v"(C.a[4]),"+v"(C.a[5]),"+v"(C.a[6]),"+v"(C.a[7]) :: "memory");
  __builtin_amdgcn_sched_barrier(0);
  f32x4 oA={0.f,0.f,0.f,0.f}, oB={0.f,0.f,0.f,0.f};
  const int kb = w*8;
  #pragma unroll
  for (int kt = 0; kt < 8; ++kt){
    const int kg = kb + kt;
    bf16x8 wh = *(const bf16x8*)(B + WO_HI_E + wo_off + kg*32);
    bf16x8 wl = *(const bf16x8*)(B + WO_LO_E + wo_off + kg*32);
    bf16x8 av = BC(C.a[kt]);
    oA = MFMA(av, wh, oA, 0,0,0);  oB = MFMA(av, wl, oB, 0,0,0);
  }
  f32x4 co = oA + oB;
  barrier_lds();   // prior RED consumers done
  if (lane < 32){
    if (w == 0) *(f32x4*)&RED[((2*3+0)*32+lane)*4] = co;
    if (w == 1) *(f32x4*)&RED[((2*3+1)*32+lane)*4] = co;
    if (w == 3) *(f32x4*)&RED[((2*3+2)*32+lane)*4] = co;
  }
  barrier_lds();
  if (w == 2 && lane < 32){
    f32x4 s = co;
    s += *(f32x4*)&RED[((2*3+0)*32+lane)*4];
    s += *(f32x4*)&RED[((2*3+1)*32+lane)*4];
    s += *(f32x4*)&RED[((2*3+2)*32+lane)*4];
    if (l15 < 2){
      #pragma unroll
      for (int r = 0; r < 4; ++r){
        int row = lhalf*4 + r;
        C.ob[((size_t)row*T_ + (T_-1))*O_ + role*2 + l15] = s[r];
      }
    }
  }
}

extern "C" __global__ __launch_bounds__(256, 1)
void rnn_kernel(const float* __restrict__ x, const float* __restrict__ noise,
                const float* __restrict__ wi, const float* __restrict__ wrec,
                const float* __restrict__ wo, float* __restrict__ out,
                u16* __restrict__ gbuf, u16* __restrict__ sflags)
{
  extern __shared__ char smem[];
  __bf16* B = (__bf16*)smem;
  float* RED = (float*)(smem + RED_OFF_B);

  const int pid  = blockIdx.x >> 5;
  const int role = blockIdx.x & 31;
  const int c0 = role * 32;

  load_slice(wrec, H_, c0, H_, B + WREC_HI_E, B + WREC_LO_E);
  load_slice(wi,   H_, c0, I_, B + WI_HI_E,  B + WI_LO_E);
  for (int idx = threadIdx.x; idx < 2*H_; idx += 256){
    int col = idx >> 10, k = idx & (H_-1);
    float v = wo[(size_t)k*O_ + role*2 + col];
    __bf16 hh = (__bf16)v;
    B[WO_HI_E + col*H_ + k] = hh;
    B[WO_LO_E + col*H_ + k] = (__bf16)(v - (float)hh);
  }
  __syncthreads();

  const int lane = threadIdx.x & 63;
  const int w    = threadIdx.x >> 6;
  const int lhalf = lane >> 4;
  const int l15   = lane & 15;
  const int bf = lane * 8;
  const int wo_off = (l15 & 1)*1024 + lhalf*8;

  Chain A, Bc;
  const int gA = pid*2, gB = pid*2+1;
  A.gg  = gbuf + gA*(2*8*H_);   A.gf  = sflags + gA*64;
  Bc.gg = gbuf + gB*(2*8*H_);   Bc.gf = sflags + gB*64;
  A.ab  = A.gg  + (size_t)(lane & 7)*H_ + w*256 + lhalf*8;
  Bc.ab = Bc.gg + (size_t)(lane & 7)*H_ + w*256 + lhalf*8;
  A.xb  = x + (size_t)(gA*8)*T_*I_;     Bc.xb = x + (size_t)(gB*8)*T_*I_;
  A.nb  = noise + (size_t)(gA*8)*T_*H_; Bc.nb = noise + (size_t)(gB*8)*T_*H_;
  A.ob  = out + (size_t)(gA*8)*T_*O_;   Bc.ob = out + (size_t)(gB*8)*T_*O_;
  A.NS  = (float*)(smem + NSA_OFF_B);   Bc.NS = (float*)(smem + NSB_OFF_B);
  A.h0  = (f32x4){0.f,0.f,0.f,0.f};     Bc.h0 = (f32x4){0.f,0.f,0.f,0.f};
  A.xA  = (f32x4){0.f,0.f,0.f,0.f};     A.xB  = (f32x4){0.f,0.f,0.f,0.f};
  Bc.xA = (f32x4){0.f,0.f,0.f,0.f};     Bc.xB = (f32x4){0.f,0.f,0.f,0.f};

  prep0(A, B, lane, w, lhalf, l15, bf, c0);

  for (int i = 0; i < T_; ++i){
    do_half(A,  Bc, i, i,   B, RED, lane, w, lhalf, l15, bf, wo_off, c0, role);
    do_half(Bc, A,  i, i+1, B, RED, lane, w, lhalf, l15, bf, wo_off, c0, role);
  }

  epi(A, B, RED, lane, w, lhalf, l15, bf, wo_off, role);
  { // fetch B's g_T (not prefetched) and finish
    int guard = 0;
    while (true){
      unsigned v = sflag_load(Bc.gf + lane);
      if (__all((int)(v >= (unsigned)T_))) break;
      if (++guard > POLL_CAP) break;
    }
    #pragma unroll
    for (int kt = 0; kt < 8; ++kt) g_load_frag(Bc.a[kt], Bc.ab + kt*32); // parity T&1==0
  }
  epi(Bc, B, RED, lane, w, lhalf, l15, bf, wo_off, role);
}

extern "C" void kernel_launch(void* const* d_in, const int* in_sizes, int n_in,
                              void* d_out, int out_size, void* d_ws, size_t ws_size,
                              hipStream_t stream){
  const float* x     = (const float*)d_in[0];
  const float* noise = (const float*)d_in[1];
  const float* wi    = (const float*)d_in[2];
  const float* wrec  = (const float*)d_in[3];
  const float* wo    = (const float*)d_in[4];
  float* out = (float*)d_out;

  if (ws_size < (size_t)WS_NEED) return;
  u16* gbuf = (u16*)d_ws;
  u16* sflags = (u16*)((char*)d_ws + STEPFLAG_OFF);

  hipMemsetAsync(d_ws, 0, WS_NEED, stream);   // zero g_0 + flags

  hipFuncSetAttribute((const void*)rnn_kernel,
                      hipFuncAttributeMaxDynamicSharedMemorySize, LDS_BYTES);

  void* args[] = {(void*)&x, (void*)&noise, (void*)&wi, (void*)&wrec, (void*)&wo,
                  (void*)&out, (void*)&gbuf, (void*)&sflags};
  hipLaunchCooperativeKernel((const void*)rnn_kernel, dim3(NWG), dim3(256),
                             args, LDS_BYTES, stream);
}